// Round 8
// baseline (112.032 us; speedup 1.0000x reference)
//
#include <hip/hip_runtime.h>
#include <hip/hip_bf16.h>
#include <stdint.h>

// out[b, p] = x[b, ii[p]] * x[b, jj[p]], (ii,jj)=triu_indices(512), row-major.
// Write-BW-bound: ~538 MB out, 2 MB in.
//
// R8: table-driven. A setup kernel precomputes, per float4 group g:
//   i (row), j0 (start col of row-i run), split = min(off(i+1)-4g, 4)
// packed into uint32 (i:9 | j0:9 | (split-1):2) in d_ws (128 KB, L2-resident).
// Main kernel inner loop: 1 coalesced dword table load + bitfield extracts +
// 2x ds_read_b128 (shifted-copy LDS) + 2 broadcast b32 + 7 muls + 3 selects.
// No sqrt, no integer muls — ~2.3x fewer VALU than R7. Discriminates
// VALU-issue-bound vs store-path ceiling.
//
// Special cases (cndmask patches, see R7): g==255 -> .w = x[2]^2 (only group
// with j1<0); g==GROUPS-1 -> .w = x[511]^2 (3-row group).

#define ELE 512
#define NPAIRS 131328            // 512*513/2
#define GROUPS 32832             // NPAIRS/4
#define BPB 8                    // blocks per batch
#define GPB 4104                 // GROUPS/BPB = 16*256 + 8

typedef float f4 __attribute__((ext_vector_type(4)));

__global__ __launch_bounds__(256) void build_tab(uint32_t* __restrict__ tab) {
    const int g = blockIdx.x * 256 + threadIdx.x;
    if (g >= GROUPS) return;
    const int p = g << 2;
    float s = sqrtf((float)(1050625 - 8 * p));
    int i = (int)((1025.0f - s) * 0.5f);
    i = min(max(i, 0), 511);
    while ((((i + 1) * (1024 - i)) >> 1) <= p) ++i;   // off(i+1) <= p
    while (((i * (1025 - i)) >> 1) > p) --i;          // off(i) > p
    const int o0 = (i * (1025 - i)) >> 1;
    const int o1 = o0 + (ELE - i);
    const int j0 = i + (p - o0);
    const int split = min(o1 - p, 4);                 // 1..4
    tab[g] = (uint32_t)i | ((uint32_t)j0 << 9) | ((uint32_t)(split - 1) << 18);
}

__device__ __forceinline__ f4 group_val(
    int g, const uint32_t* __restrict__ tab,
    const float (*xs4)[516], float g255sq, float lastsq) {
    const uint32_t u = tab[g];
    const int i     = u & 511;
    const int j0    = (u >> 9) & 511;
    const int split = ((u >> 18) & 3) + 1;
    int j1 = j0 + i - 511;               // j0 + 1 - (512-i)
    j1 = max(j1, 0);                     // only g==255 clamps (patched below)

    const f4 r0 = ((const f4*)xs4[j0 & 3])[j0 >> 2];
    const f4 r1 = ((const f4*)xs4[j1 & 3])[j1 >> 2];
    const float xi0 = xs4[0][i];
    const float xi1 = xs4[0][i + 1];     // slot 512 zero-padded

    f4 v;
    v.x = xi0 * r0.x;                    // split >= 1 always
    v.y = (1 < split) ? xi0 * r0.y : xi1 * r1.y;
    v.z = (2 < split) ? xi0 * r0.z : xi1 * r1.z;
    v.w = (3 < split) ? xi0 * r0.w : xi1 * r1.w;
    v.w = (g == 255) ? g255sq : v.w;
    v.w = (g == GROUPS - 1) ? lastsq : v.w;
    return v;
}

__global__ __launch_bounds__(256) void pairmul4_tab_kernel(
    const float* __restrict__ X, float* __restrict__ out,
    const uint32_t* __restrict__ tab) {
    const int bid = blockIdx.x;
    const int b = bid >> 3;        // batch
    const int c = bid & 7;         // chunk within batch

    const float* __restrict__ xb = X + (size_t)b * ELE;
    f4* __restrict__ ob = (f4*)(out + (size_t)b * NPAIRS);

    // 4 shifted copies, stride 516 floats (2064 B, 16B-aligned rows).
    __shared__ __align__(16) float xs4[4][516];
    const int t = threadIdx.x;
    #pragma unroll
    for (int cc = 0; cc < 4; ++cc) {
        xs4[cc][t] = xb[t + cc];
        const int m1 = t + 256;
        xs4[cc][m1] = (m1 + cc < ELE) ? xb[m1 + cc] : 0.0f;
    }
    if (t < 16) xs4[t & 3][512 + (t >> 2)] = 0.0f;     // pad slots
    __syncthreads();

    const float x511 = xs4[0][511];
    const float lastsq = x511 * x511;                  // pair (511,511)
    const float x2 = xs4[0][2];
    const float g255sq = x2 * x2;                      // pair (2,2)

    const int glo = c * GPB;

    #pragma unroll 4
    for (int k = 0; k < 16; ++k) {
        const int g = glo + t + (k << 8);
        ob[g] = group_val(g, tab, xs4, g255sq, lastsq);
    }
    if (t < 8) {                                       // GPB tail (8 groups)
        const int g = glo + 4096 + t;
        ob[g] = group_val(g, tab, xs4, g255sq, lastsq);
    }
}

// Fallback (R7, self-contained) if ws_size can't hold the table.
__global__ __launch_bounds__(256) void pairmul4_kernel(
    const float* __restrict__ X, float* __restrict__ out) {
    const int bid = blockIdx.x;
    const int b = bid >> 3;
    const int c = bid & 7;
    const float* __restrict__ xb = X + (size_t)b * ELE;
    f4* __restrict__ ob = (f4*)(out + (size_t)b * NPAIRS);
    __shared__ __align__(16) float xs4[4][516];
    const int t = threadIdx.x;
    #pragma unroll
    for (int cc = 0; cc < 4; ++cc) {
        xs4[cc][t] = xb[t + cc];
        const int m1 = t + 256;
        xs4[cc][m1] = (m1 + cc < ELE) ? xb[m1 + cc] : 0.0f;
    }
    if (t < 16) xs4[t & 3][512 + (t >> 2)] = 0.0f;
    __syncthreads();
    const float x511 = xs4[0][511];
    const float lastsq = x511 * x511;
    const float x2 = xs4[0][2];
    const float g255sq = x2 * x2;
    const int glo = c * GPB;
    const int ghi = glo + GPB;
    for (int g = glo + t; g < ghi; g += 256) {
        const int p = g << 2;
        const float s = sqrtf((float)(1050625 - 8 * p));
        int i = (int)((1025.0f - s) * 0.5f);
        i = min(max(i, 0), 511);
        int onext = ((i + 1) * (1024 - i)) >> 1;
        i += (p >= onext);
        onext = ((i + 1) * (1024 - i)) >> 1;
        i += (p >= onext);
        int ocur = (i * (1025 - i)) >> 1;
        i -= (p < ocur);
        const int o0 = (i * (1025 - i)) >> 1;
        const int L  = ELE - i;
        const int o1 = o0 + L;
        const int j0 = i + (p - o0);
        int j1 = j0 + 1 - L;
        j1 = max(j1, 0);
        const f4 r0 = ((const f4*)xs4[j0 & 3])[j0 >> 2];
        const f4 r1 = ((const f4*)xs4[j1 & 3])[j1 >> 2];
        const float xi0 = xs4[0][i];
        const float xi1 = xs4[0][i + 1];
        const int split = o1 - p;
        f4 v;
        v.x = (0 < split) ? xi0 * r0.x : xi1 * r1.x;
        v.y = (1 < split) ? xi0 * r0.y : xi1 * r1.y;
        v.z = (2 < split) ? xi0 * r0.z : xi1 * r1.z;
        v.w = (3 < split) ? xi0 * r0.w : xi1 * r1.w;
        v.w = (g == 255) ? g255sq : v.w;
        v.w = (g == GROUPS - 1) ? lastsq : v.w;
        ob[g] = v;
    }
}

extern "C" void kernel_launch(void* const* d_in, const int* in_sizes, int n_in,
                              void* d_out, int out_size, void* d_ws, size_t ws_size,
                              hipStream_t stream) {
    const float* X = (const float*)d_in[0];
    float* out = (float*)d_out;
    const int B = in_sizes[0] / ELE;   // 1024

    if (ws_size >= (size_t)GROUPS * sizeof(uint32_t)) {
        uint32_t* tab = (uint32_t*)d_ws;
        build_tab<<<(GROUPS + 255) / 256, 256, 0, stream>>>(tab);
        pairmul4_tab_kernel<<<dim3(B * BPB), dim3(256), 0, stream>>>(X, out, tab);
    } else {
        pairmul4_kernel<<<dim3(B * BPB), dim3(256), 0, stream>>>(X, out);
    }
}